// Round 1
// baseline (256.326 us; speedup 1.0000x reference)
//
#include <hip/hip_runtime.h>
#include <math.h>

#define SE_B   32
#define SE_C   256
#define SE_HID 16
#define SE_HW  4096   // 64*64
#define SE_HW4 1024   // float4 per (b,c) plane

// Kernel 1: per-(b,c) plane mean. One 256-thread block per plane.
__global__ __launch_bounds__(256) void se_mean_kernel(const float* __restrict__ x,
                                                      float* __restrict__ s) {
    const int plane = blockIdx.x;  // b*C + c
    const float4* xp = (const float4*)x + (size_t)plane * SE_HW4;
    const int tid = threadIdx.x;

    float sum = 0.f;
#pragma unroll
    for (int k = 0; k < 4; ++k) {
        float4 v = xp[tid + k * 256];
        sum += (v.x + v.y) + (v.z + v.w);
    }
    // wave(64)-level reduction
#pragma unroll
    for (int off = 32; off > 0; off >>= 1) sum += __shfl_down(sum, off, 64);

    __shared__ float part[4];
    if ((tid & 63) == 0) part[tid >> 6] = sum;
    __syncthreads();
    if (tid == 0) {
        float tot = (part[0] + part[1]) + (part[2] + part[3]);
        s[plane] = tot * (1.0f / SE_HW);
    }
}

// Kernel 2: tiny channel MLP: h = relu(s@w1^T + b1); g = sigmoid(h@w2^T + b2).
// One block per batch element.
__global__ __launch_bounds__(256) void se_gate_kernel(const float* __restrict__ s,
                                                      const float* __restrict__ w1,
                                                      const float* __restrict__ b1,
                                                      const float* __restrict__ w2,
                                                      const float* __restrict__ b2,
                                                      float* __restrict__ g) {
    const int b = blockIdx.x;
    const int tid = threadIdx.x;

    __shared__ float s_sh[SE_C];
    __shared__ float h_sh[SE_HID];

    s_sh[tid] = s[b * SE_C + tid];
    __syncthreads();

    if (tid < SE_HID) {
        float acc = b1[tid];
        const float* w1r = w1 + tid * SE_C;
        for (int c = 0; c < SE_C; ++c) acc = fmaf(s_sh[c], w1r[c], acc);
        h_sh[tid] = fmaxf(acc, 0.f);
    }
    __syncthreads();

    float acc = b2[tid];
    const float* w2r = w2 + tid * SE_HID;
#pragma unroll
    for (int h = 0; h < SE_HID; ++h) acc = fmaf(h_sh[h], w2r[h], acc);
    g[b * SE_C + tid] = 1.0f / (1.0f + expf(-acc));
}

// Kernel 3: out = x * g[plane], float4 grid-stride.
__global__ __launch_bounds__(256) void se_scale_kernel(const float* __restrict__ x,
                                                       const float* __restrict__ g,
                                                       float* __restrict__ out) {
    const int total4 = SE_B * SE_C * SE_HW4;  // 8,388,608
    const float4* xp = (const float4*)x;
    float4* op = (float4*)out;
    const int stride = gridDim.x * blockDim.x;
    for (int idx = blockIdx.x * blockDim.x + threadIdx.x; idx < total4; idx += stride) {
        const float gv = g[idx >> 10];  // 1024 float4 per plane
        float4 v = xp[idx];
        v.x *= gv; v.y *= gv; v.z *= gv; v.w *= gv;
        op[idx] = v;
    }
}

extern "C" void kernel_launch(void* const* d_in, const int* in_sizes, int n_in,
                              void* d_out, int out_size, void* d_ws, size_t ws_size,
                              hipStream_t stream) {
    const float* x  = (const float*)d_in[0];
    const float* w1 = (const float*)d_in[1];
    const float* b1 = (const float*)d_in[2];
    const float* w2 = (const float*)d_in[3];
    const float* b2 = (const float*)d_in[4];
    float* out = (float*)d_out;

    float* s = (float*)d_ws;            // [B*C]
    float* g = s + SE_B * SE_C;         // [B*C]

    se_mean_kernel<<<SE_B * SE_C, 256, 0, stream>>>(x, s);
    se_gate_kernel<<<SE_B, 256, 0, stream>>>(s, w1, b1, w2, b2, g);
    se_scale_kernel<<<8192, 256, 0, stream>>>(x, g, out);
}

// Round 2
// 249.876 us; speedup vs baseline: 1.0258x; 1.0258x over previous
//
#include <hip/hip_runtime.h>
#include <math.h>

#define SE_B   32
#define SE_C   256
#define SE_HID 16
#define SE_HW  4096   // 64*64
#define SE_HW4 1024   // float4 per (b,c) plane

typedef float f4v __attribute__((ext_vector_type(4)));

// Kernel 1: per-(b,c) plane mean. One 256-thread block per plane.
// Normal (caching) loads on purpose: leaves x resident in the 256 MiB L3
// so the scale pass can re-read it without HBM traffic.
__global__ __launch_bounds__(256) void se_mean_kernel(const float* __restrict__ x,
                                                      float* __restrict__ s) {
    const int plane = blockIdx.x;  // b*C + c
    const float4* xp = (const float4*)x + (size_t)plane * SE_HW4;
    const int tid = threadIdx.x;

    float sum = 0.f;
#pragma unroll
    for (int k = 0; k < 4; ++k) {
        float4 v = xp[tid + k * 256];
        sum += (v.x + v.y) + (v.z + v.w);
    }
#pragma unroll
    for (int off = 32; off > 0; off >>= 1) sum += __shfl_down(sum, off, 64);

    __shared__ float part[4];
    if ((tid & 63) == 0) part[tid >> 6] = sum;
    __syncthreads();
    if (tid == 0) {
        float tot = (part[0] + part[1]) + (part[2] + part[3]);
        s[plane] = tot * (1.0f / SE_HW);
    }
}

// Kernel 2: fused gate + scale. One 256-thread block per (b,c) plane.
// Each block redundantly computes its own gate scalar (4096 MACs — free,
// hidden under the plane's x loads), then multiplies and NT-stores so the
// 128 MiB of output writes don't evict x from L3.
__global__ __launch_bounds__(256) void se_scale_kernel(const float* __restrict__ x,
                                                       const float* __restrict__ s,
                                                       const float* __restrict__ w1,
                                                       const float* __restrict__ b1,
                                                       const float* __restrict__ w2,
                                                       const float* __restrict__ b2,
                                                       float* __restrict__ out) {
    const int plane = blockIdx.x;
    const int b = plane >> 8;    // / SE_C
    const int c = plane & 255;   // % SE_C
    const int tid = threadIdx.x;

    const float4* xp = (const float4*)x + (size_t)plane * SE_HW4;
    float4* op = (float4*)out + (size_t)plane * SE_HW4;

    // Issue the plane's x loads first; gate math overlaps their latency.
    float4 v0 = xp[tid];
    float4 v1 = xp[tid + 256];
    float4 v2 = xp[tid + 512];
    float4 v3 = xp[tid + 768];

    // Gate: h_i = relu(b1_i + sum_c' s[b,c']*w1[i,c']);
    //       g   = sigmoid(b2_c + sum_i h_i*w2[c,i])
    __shared__ float part[16][17];   // [chunk j][hidden i], +1 col padding
    __shared__ float g_sh;

    const int i = tid & 15;   // hidden unit
    const int j = tid >> 4;   // chunk of 16 channels
    {
        const float* srow = s  + b * SE_C  + j * 16;
        const float* wrow = w1 + i * SE_C  + j * 16;
        float p = 0.f;
#pragma unroll
        for (int k = 0; k < 16; ++k) p = fmaf(srow[k], wrow[k], p);
        part[j][i] = p;
    }
    __syncthreads();
    if (tid < SE_HID) {
        float acc = b1[tid];
#pragma unroll
        for (int k = 0; k < 16; ++k) acc += part[k][tid];   // column tid only
        part[0][tid] = fmaxf(acc, 0.f);                     // reuse row 0 as h[]
    }
    __syncthreads();
    if (tid == 0) {
        float acc = b2[c];
        const float* w2r = w2 + c * SE_HID;
#pragma unroll
        for (int k = 0; k < 16; ++k) acc = fmaf(part[0][k], w2r[k], acc);
        g_sh = 1.0f / (1.0f + expf(-acc));
    }
    __syncthreads();
    const float g = g_sh;

    v0.x *= g; v0.y *= g; v0.z *= g; v0.w *= g;
    v1.x *= g; v1.y *= g; v1.z *= g; v1.w *= g;
    v2.x *= g; v2.y *= g; v2.z *= g; v2.w *= g;
    v3.x *= g; v3.y *= g; v3.z *= g; v3.w *= g;

    __builtin_nontemporal_store(*(f4v*)&v0, (f4v*)(op + tid));
    __builtin_nontemporal_store(*(f4v*)&v1, (f4v*)(op + tid + 256));
    __builtin_nontemporal_store(*(f4v*)&v2, (f4v*)(op + tid + 512));
    __builtin_nontemporal_store(*(f4v*)&v3, (f4v*)(op + tid + 768));
}

extern "C" void kernel_launch(void* const* d_in, const int* in_sizes, int n_in,
                              void* d_out, int out_size, void* d_ws, size_t ws_size,
                              hipStream_t stream) {
    const float* x  = (const float*)d_in[0];
    const float* w1 = (const float*)d_in[1];
    const float* b1 = (const float*)d_in[2];
    const float* w2 = (const float*)d_in[3];
    const float* b2 = (const float*)d_in[4];
    float* out = (float*)d_out;

    float* s = (float*)d_ws;  // [B*C] plane means

    se_mean_kernel<<<SE_B * SE_C, 256, 0, stream>>>(x, s);
    se_scale_kernel<<<SE_B * SE_C, 256, 0, stream>>>(x, s, w1, b1, w2, b2, out);
}